// Round 2
// baseline (117.690 us; speedup 1.0000x reference)
//
#include <hip/hip_runtime.h>
#include <math.h>

// Problem constants (from reference setup_inputs)
#define BS 64      // batch
#define F  256     // features (K of the Gram matmul)
#define M  128     // columns  (M=N of the Gram matmul)
#define MF (M * F) // u16 elements per matrix in hT
#define NBP 1056   // blocks per mat: sum_a ceil((64-a)/2)

typedef unsigned short u16;
typedef _Float16 f16x8 __attribute__((ext_vector_type(8)));
typedef float    f32x16 __attribute__((ext_vector_type(16)));

// ---------------------------------------------------------------------------
// Pre-pass: fp32 [f][m] -> fp16 GRANULE-MAJOR hT[b][f8][m][8]. (round 6:
// coalesced staging worth 107->58 us; layout verified.)
// ---------------------------------------------------------------------------
__global__ __launch_bounds__(256) void convert_f16_kernel(
    const float* __restrict__ m1, const float* __restrict__ m2,
    u16* __restrict__ hT)
{
    __shared__ float tile[64 * M];   // 32 KB
    const int mat = blockIdx.x >> 6;
    const int b   = blockIdx.x & 63;
    const int f0  = blockIdx.y * 64;
    const float* src = (mat == 0 ? m1 : m2) + (size_t)b * MF + (size_t)f0 * M;
    const int tid = threadIdx.x;

    const float4* g = (const float4*)src;
    float4* s = (float4*)tile;
    #pragma unroll
    for (int i = 0; i < 8; ++i)
        s[tid + i * 256] = g[tid + i * 256];
    __syncthreads();

    const size_t obase = ((size_t)(mat * BS + b) * 32 + (f0 >> 3)) * 1024;
    #pragma unroll
    for (int it = 0; it < 4; ++it) {
        const int idx = it * 256 + tid;
        const int f8l = idx >> 7;
        const int m   = idx & 127;
        u16 hh[8] __attribute__((aligned(16)));
        #pragma unroll
        for (int j = 0; j < 8; ++j) {
            const float x = tile[(f8l * 8 + j) * M + m];  // 2 lanes/bank: free
            const _Float16 h = (_Float16)x;               // RNE
            hh[j] = __builtin_bit_cast(u16, h);
        }
        *(uint4*)&hT[obase + (size_t)idx * 8] = *(const uint4*)hh;
    }
}

// ---------------------------------------------------------------------------
// ROUND 10: occupancy was the wall (2 waves/SIMD at 212 regs/wave; MfmaUtil
// 27% / VALUBusy 44% with both pipes idle waiting on barriers+latency).
// Restructure: 512-thread blocks, 8 waves, wave w=(pp,rh,ch) owns a 64x64
// sub-tile of pair pp -> acc = 4 x f32x16 = 64 AGPR; __launch_bounds__(512,4)
// targets 128 regs/wave -> 2 blocks/CU = 4 waves/SIMD (2x latency hiding).
// A (4x wave reuse) stays LDS-staged (1 uint4/thread/chunk, double-buffered);
// B fragments load DIRECT global->VGPR (hT granule-major layout IS the
// fragment layout), 1-iteration prefetch into double-buffered named reg sets
// (manual unroll-by-2: no rotation movs, LDS offsets are immediates).
// Epilogue per-thread work halves (64 values). Reg budget: 64 AGPR +
// ~60 arch VGPR (af 8 transient, bA/bB 32, rA 4, addrs/misc ~16) <= 128.
// ---------------------------------------------------------------------------

#define LOADB(DST, CH) {                                      \
    const u16* pbk = pb + (CH) * 4096;                        \
    DST[0][0] = *(const f16x8*)(pbk);                         \
    DST[0][1] = *(const f16x8*)(pbk + 256);                   \
    DST[1][0] = *(const f16x8*)(pbk + 2048);                  \
    DST[1][1] = *(const f16x8*)(pbk + 2048 + 256);            \
}

#define MFMA_PHASE(CUR, BF) {                                                                   \
    const f16x8 a00 = *(const f16x8*)&lds[(CUR) + aoff];                                        \
    const f16x8 a01 = *(const f16x8*)&lds[(CUR) + aoff + 256];                                  \
    acc[0][0] = __builtin_amdgcn_mfma_f32_32x32x16_f16(a00, BF[0][0], acc[0][0], 0, 0, 0);      \
    acc[0][1] = __builtin_amdgcn_mfma_f32_32x32x16_f16(a00, BF[0][1], acc[0][1], 0, 0, 0);      \
    acc[1][0] = __builtin_amdgcn_mfma_f32_32x32x16_f16(a01, BF[0][0], acc[1][0], 0, 0, 0);      \
    acc[1][1] = __builtin_amdgcn_mfma_f32_32x32x16_f16(a01, BF[0][1], acc[1][1], 0, 0, 0);      \
    const f16x8 a10 = *(const f16x8*)&lds[(CUR) + 2048 + aoff];                                 \
    const f16x8 a11 = *(const f16x8*)&lds[(CUR) + 2048 + aoff + 256];                           \
    acc[0][0] = __builtin_amdgcn_mfma_f32_32x32x16_f16(a10, BF[1][0], acc[0][0], 0, 0, 0);      \
    acc[0][1] = __builtin_amdgcn_mfma_f32_32x32x16_f16(a10, BF[1][1], acc[0][1], 0, 0, 0);      \
    acc[1][0] = __builtin_amdgcn_mfma_f32_32x32x16_f16(a11, BF[1][0], acc[1][0], 0, 0, 0);      \
    acc[1][1] = __builtin_amdgcn_mfma_f32_32x32x16_f16(a11, BF[1][1], acc[1][1], 0, 0, 0);      \
}

__global__ __launch_bounds__(512, 4) void gram_hist_mfma(
    const u16* __restrict__ hT, float* __restrict__ out)
{
    __shared__ u16 lds[2 * 4096];   // 16 KB: A tiles only, double-buffered
    __shared__ float smin[8], smax[8];
    __shared__ int hist[2][8];

    const int tid  = threadIdx.x;
    const int lane = tid & 63;
    const int w    = tid >> 6;

    if (tid < 16) hist[tid >> 3][tid & 7] = 0;

    // Decode blockIdx.x -> (a, p) with per-a count ceil((64-a)/2).
    int p = blockIdx.x, a = 0;
    { int cnt = 32; while (p >= cnt) { p -= cnt; ++a; cnt = (64 - a + 1) >> 1; } }
    const int b1 = a + 2 * p;
    int b2 = b1 + 1;
    const bool b2valid = (b2 <= 63);
    if (!b2valid) b2 = b1;          // duplicate work, writes suppressed
    const int mat = blockIdx.y;

    const int pp = w >> 2;     // which pair (0: b1, 1: b2)
    const int rh = (w >> 1) & 1;  // 64-row half
    const int ch = w & 1;         // 64-col half
    const int l31   = lane & 31;
    const int lhalf = lane >> 5;

    // A staging: 512 threads x 8 u16 = one 4096-u16 chunk per ds_write.
    const u16* pa = hT + (size_t)(mat * BS + a) * MF + tid * 8;
    const int d0 = tid * 8;

    // A fragment LDS offset (u16 units): addr(kk) = kk*2048 + aoff (+256 for ti=1)
    //   = (kb*128 + rh*64 + ti*32 + l31)*8, kb = kk*2 + lhalf
    const int aoff = lhalf * 1024 + (rh * 64 + l31) * 8;

    // B fragment global base: frag(it,kk,u) = pb + it*4096 + kk*2048 + u*256
    //   = ((kk*2+lhalf)*128 + ch*64 + u*32 + l31)*8 within chunk
    const int bsel = pp ? b2 : b1;
    const u16* pb = hT + (size_t)(mat * BS + bsel) * MF
                  + (size_t)(lhalf * 1024 + ch * 512 + l31 * 8);

    f32x16 acc[2][2];
    #pragma unroll
    for (int ti = 0; ti < 2; ++ti)
        #pragma unroll
        for (int u = 0; u < 2; ++u)
            #pragma unroll
            for (int r = 0; r < 16; ++r) acc[ti][u][r] = 0.0f;

    uint4 rA;
    f16x8 bA[2][2], bB[2][2];   // double-buffered B fragment sets

    // ---- prologue: A chunk 0 -> LDS, B frags chunk 0 -> bA ----
    rA = *(const uint4*)pa;
    LOADB(bA, 0);
    *(uint4*)&lds[d0] = rA;
    __syncthreads();

    #pragma unroll
    for (int itp = 0; itp < 4; ++itp) {
        // even it = 2*itp, cur = buf0: prefetch chunk 2*itp+1 into bB/buf1
        {
            const int nxt = 2 * itp + 1;
            rA = *(const uint4*)(pa + nxt * 4096);
            LOADB(bB, nxt);
            MFMA_PHASE(0, bA);
            *(uint4*)&lds[4096 + d0] = rA;
            __syncthreads();
        }
        // odd it = 2*itp+1, cur = buf1: prefetch chunk 2*itp+2 into bA/buf0
        {
            if (itp < 3) {
                const int nxt = 2 * itp + 2;
                rA = *(const uint4*)(pa + nxt * 4096);
                LOADB(bA, nxt);
            }
            MFMA_PHASE(4096, bB);
            if (itp < 3) {
                *(uint4*)&lds[d0] = rA;
                __syncthreads();
            }
        }
    }

    // ---- epilogue: pair pp owned by waves pp*4 .. pp*4+3 ----
    float vmin = acc[0][0][0], vmax = vmin;
    #pragma unroll
    for (int ti = 0; ti < 2; ++ti)
        #pragma unroll
        for (int u = 0; u < 2; ++u)
            #pragma unroll
            for (int r = 0; r < 16; ++r) {
                vmin = fminf(vmin, acc[ti][u][r]);
                vmax = fmaxf(vmax, acc[ti][u][r]);
            }
    #pragma unroll
    for (int off = 1; off < 64; off <<= 1) {
        vmin = fminf(vmin, __shfl_xor(vmin, off, 64));
        vmax = fmaxf(vmax, __shfl_xor(vmax, off, 64));
    }
    if (lane == 0) { smin[w] = vmin; smax[w] = vmax; }
    __syncthreads();
    const int pb4 = pp * 4;
    const float pmn = fminf(fminf(smin[pb4], smin[pb4 + 1]),
                            fminf(smin[pb4 + 2], smin[pb4 + 3]));
    const float pmx = fmaxf(fmaxf(smax[pb4], smax[pb4 + 1]),
                            fmaxf(smax[pb4 + 2], smax[pb4 + 3]));
    const float denom = (pmx > pmn) ? (pmx - pmn) : 1.0f;
    const float scale = 8.0f / denom;
    const float bias  = -pmn * scale;

    // per-thread packed histogram: 64 values -> 8-bit fields (<=64/bin)
    unsigned w0 = 0, w1 = 0;
    #pragma unroll
    for (int ti = 0; ti < 2; ++ti)
        #pragma unroll
        for (int u = 0; u < 2; ++u)
            #pragma unroll
            for (int r = 0; r < 16; ++r) {
                const float t = fmaf(acc[ti][u][r], scale, bias);
                int k = (int)t;          // t >= -eps; trunc == floor
                k = k > 7 ? 7 : k;
                const unsigned inc = 1u << ((k & 3) * 8);
                if (k < 4) w0 += inc; else w1 += inc;
            }
    unsigned e0 = (w0 & 0xFFu)         | (((w0 >> 8)  & 0xFFu) << 16);
    unsigned e1 = ((w0 >> 16) & 0xFFu) | (((w0 >> 24) & 0xFFu) << 16);
    unsigned e2 = (w1 & 0xFFu)         | (((w1 >> 8)  & 0xFFu) << 16);
    unsigned e3 = ((w1 >> 16) & 0xFFu) | (((w1 >> 24) & 0xFFu) << 16);
    #pragma unroll
    for (int off = 32; off > 0; off >>= 1) {
        e0 += __shfl_down(e0, off, 64);
        e1 += __shfl_down(e1, off, 64);
        e2 += __shfl_down(e2, off, 64);
        e3 += __shfl_down(e3, off, 64);
    }
    if (lane == 0) {
        atomicAdd(&hist[pp][0], (int)(e0 & 0xFFFFu)); atomicAdd(&hist[pp][1], (int)(e0 >> 16));
        atomicAdd(&hist[pp][2], (int)(e1 & 0xFFFFu)); atomicAdd(&hist[pp][3], (int)(e1 >> 16));
        atomicAdd(&hist[pp][4], (int)(e2 & 0xFFFFu)); atomicAdd(&hist[pp][5], (int)(e2 >> 16));
        atomicAdd(&hist[pp][6], (int)(e3 & 0xFFFFu)); atomicAdd(&hist[pp][7], (int)(e3 >> 16));
    }
    __syncthreads();

    // one wave per pair normalizes and writes both symmetric rows
    const int B = (pp == 0) ? b1 : b2;
    const bool valid = (pp == 0) || b2valid;
    if (valid && rh == 0 && ch == 0 && lane < 8) {
        float ss = 0.0f;
        #pragma unroll
        for (int k = 0; k < 8; ++k) {
            const float cc = (float)hist[pp][k];
            ss += cc * cc;
        }
        const float nrm = fmaxf(sqrtf(ss), 1e-12f);
        const float v = (float)hist[pp][lane] / nrm;
        out[((size_t)a * BS + B) * 16 + mat * 8 + lane] = v;
        if (a != B)
            out[((size_t)B * BS + a) * 16 + mat * 8 + lane] = v;
    }
}

extern "C" void kernel_launch(void* const* d_in, const int* in_sizes, int n_in,
                              void* d_out, int out_size, void* d_ws, size_t ws_size,
                              hipStream_t stream) {
    const float* m1 = (const float*)d_in[0];
    const float* m2 = (const float*)d_in[1];
    float* out = (float*)d_out;

    // Workspace: granule-major fp16 array, 2*64*128*256 u16 = 8.39 MB.
    u16* hT = (u16*)d_ws;

    convert_f16_kernel<<<dim3(128, 4), 256, 0, stream>>>(m1, m2, hT);
    gram_hist_mfma<<<dim3(NBP, 2), 512, 0, stream>>>(hT, out);
}

// Round 3
// 116.068 us; speedup vs baseline: 1.0140x; 1.0140x over previous
//
#include <hip/hip_runtime.h>
#include <math.h>

// Problem constants (from reference setup_inputs)
#define BS 64      // batch
#define F  256     // features (K of the Gram matmul)
#define M  128     // columns  (M=N of the Gram matmul)
#define MF (M * F) // u16 elements per matrix in hT
#define NBP 1056   // blocks per mat: sum_a ceil((64-a)/2)

typedef unsigned short u16;
typedef _Float16 f16x8 __attribute__((ext_vector_type(8)));
typedef float    f32x16 __attribute__((ext_vector_type(16)));

// ---------------------------------------------------------------------------
// Pre-pass: fp32 [f][m] -> fp16 GRANULE-MAJOR hT[b][f8][m][8]. (round 6:
// coalesced staging worth 107->58 us; layout verified.)
// ---------------------------------------------------------------------------
__global__ __launch_bounds__(256) void convert_f16_kernel(
    const float* __restrict__ m1, const float* __restrict__ m2,
    u16* __restrict__ hT)
{
    __shared__ float tile[64 * M];   // 32 KB
    const int mat = blockIdx.x >> 6;
    const int b   = blockIdx.x & 63;
    const int f0  = blockIdx.y * 64;
    const float* src = (mat == 0 ? m1 : m2) + (size_t)b * MF + (size_t)f0 * M;
    const int tid = threadIdx.x;

    const float4* g = (const float4*)src;
    float4* s = (float4*)tile;
    #pragma unroll
    for (int i = 0; i < 8; ++i)
        s[tid + i * 256] = g[tid + i * 256];
    __syncthreads();

    const size_t obase = ((size_t)(mat * BS + b) * 32 + (f0 >> 3)) * 1024;
    #pragma unroll
    for (int it = 0; it < 4; ++it) {
        const int idx = it * 256 + tid;
        const int f8l = idx >> 7;
        const int m   = idx & 127;
        u16 hh[8] __attribute__((aligned(16)));
        #pragma unroll
        for (int j = 0; j < 8; ++j) {
            const float x = tile[(f8l * 8 + j) * M + m];  // 2 lanes/bank: free
            const _Float16 h = (_Float16)x;               // RNE
            hh[j] = __builtin_bit_cast(u16, h);
        }
        *(uint4*)&hT[obase + (size_t)idx * 8] = *(const uint4*)hh;
    }
}

// ---------------------------------------------------------------------------
// ROUND 11 (post-mortem of r9/r10): MfmaUtil*dur is CONSTANT across all
// structures (~14.5 us-equiv = the fixed MFMA work at 32 cyc/MFMA/SIMD);
// the other ~50% of SIMD time is WAIT at the 8 per-chunk barriers (VALU 43%
// + MFMA 27% co-issuable pipes don't fill the budget). Occupancy was proven
// NOT the lever (r10: occ 24->34%, perf regressed).
// FIX: A is only 64 KB fp16 -> load ALL of A into LDS once, ONE barrier,
// then a ZERO-BARRIER main loop: 8 chunks x 16 MFMA = 128 back-to-back
// MFMAs per wave, gated only by operand readiness. B fragments register-
// prefetched direct from global (granule-major layout IS fragment layout,
// verified r9); no cross-wave B duplication (c splits columns). All A
// ds_read addresses = base + 16-bit immediate (max 65520 B < 64 KiB).
// Shape = round-9's best: 256T/4 waves, wave (pp,c) owns 128x64 of pair pp,
// acc = 8 x f32x16 = 128 AGPR, ~212 regs -> 2 waves/SIMD, 2 blocks/CU
// (LDS 64 KB x 2 = 128 < 160 KB).
// ---------------------------------------------------------------------------

#define LOADB(DST, IT) {                                      \
    const u16* pbk = pb + (IT) * 4096;                        \
    DST[0][0] = *(const f16x8*)(pbk);                         \
    DST[0][1] = *(const f16x8*)(pbk + 256);                   \
    DST[1][0] = *(const f16x8*)(pbk + 2048);                  \
    DST[1][1] = *(const f16x8*)(pbk + 2048 + 256);            \
}

// Chunk IT (K=32): kk=0 uses f8-groups {IT*4+lhalf}, kk=1 {IT*4+2+lhalf}.
// A frag (kk,t): lds[(IT*4 + kk*2)*1024 + t*256 + abase],
//   abase = lhalf*1024 + l31*8  (u16 units; byte offsets all < 65536).
#define MFMA_CHUNK(IT, BF) {                                                                        \
    f16x8 af[4];                                                                                    \
    _Pragma("unroll")                                                                               \
    for (int t = 0; t < 4; ++t)                                                                     \
        af[t] = *(const f16x8*)&lds[(IT) * 4096 + t * 256 + abase];                                 \
    _Pragma("unroll")                                                                               \
    for (int ti = 0; ti < 4; ++ti) {                                                                \
        acc[ti][0] = __builtin_amdgcn_mfma_f32_32x32x16_f16(af[ti], BF[0][0], acc[ti][0], 0, 0, 0); \
        acc[ti][1] = __builtin_amdgcn_mfma_f32_32x32x16_f16(af[ti], BF[0][1], acc[ti][1], 0, 0, 0); \
    }                                                                                               \
    _Pragma("unroll")                                                                               \
    for (int t = 0; t < 4; ++t)                                                                     \
        af[t] = *(const f16x8*)&lds[(IT) * 4096 + 2048 + t * 256 + abase];                          \
    _Pragma("unroll")                                                                               \
    for (int ti = 0; ti < 4; ++ti) {                                                                \
        acc[ti][0] = __builtin_amdgcn_mfma_f32_32x32x16_f16(af[ti], BF[1][0], acc[ti][0], 0, 0, 0); \
        acc[ti][1] = __builtin_amdgcn_mfma_f32_32x32x16_f16(af[ti], BF[1][1], acc[ti][1], 0, 0, 0); \
    }                                                                                               \
}

__global__ __launch_bounds__(256, 2) void gram_hist_mfma(
    const u16* __restrict__ hT, float* __restrict__ out)
{
    __shared__ u16 lds[32768];       // 64 KB: ENTIRE A matrix, granule-major
    __shared__ float smin[4], smax[4];
    __shared__ int hist[2][8];

    const int tid  = threadIdx.x;
    const int lane = tid & 63;
    const int w    = tid >> 6;

    if (tid < 16) hist[tid >> 3][tid & 7] = 0;

    // Decode blockIdx.x -> (a, p) with per-a count ceil((64-a)/2).
    int p = blockIdx.x, a = 0;
    { int cnt = 32; while (p >= cnt) { p -= cnt; ++a; cnt = (64 - a + 1) >> 1; } }
    const int b1 = a + 2 * p;
    int b2 = b1 + 1;
    const bool b2valid = (b2 <= 63);
    if (!b2valid) b2 = b1;          // duplicate work, writes suppressed
    const int mat = blockIdx.y;

    const int pp = w >> 1;     // which pair (0: b1, 1: b2)
    const int c  = w & 1;      // which 64-col half
    const int l31   = lane & 31;
    const int lhalf = lane >> 5;

    // B fragment per-lane base (u16 units):
    //   frag(it,kk,u) = pb + it*4096 + kk*2048 + u*256
    const int bsel = pp ? b2 : b1;
    const u16* pb = hT + (size_t)(mat * BS + bsel) * MF
                  + (size_t)(lhalf * 1024 + c * 512 + l31 * 8);

    // A source for whole-matrix staging.
    const u16* pa = hT + (size_t)(mat * BS + a) * MF + tid * 8;

    // A fragment per-lane LDS base (u16 units).
    const int abase = lhalf * 1024 + l31 * 8;

    f32x16 acc[4][2];
    #pragma unroll
    for (int ti = 0; ti < 4; ++ti)
        #pragma unroll
        for (int u = 0; u < 2; ++u)
            #pragma unroll
            for (int r = 0; r < 16; ++r) acc[ti][u][r] = 0.0f;

    f16x8 bA[2][2], bB[2][2];   // double-buffered B fragment sets

    // B chunk-0 prefetch first: independent of LDS, overlaps the A staging.
    LOADB(bA, 0);

    // ---- stage ENTIRE A (64 KB): 16 x (global uint4 -> LDS) per thread ----
    #pragma unroll
    for (int i = 0; i < 16; ++i) {
        const uint4 v = *(const uint4*)(pa + i * 2048);     // (tid+i*256)*8
        *(uint4*)&lds[(tid + i * 256) * 8] = v;
    }
    __syncthreads();   // THE ONLY BARRIER before the epilogue

    // ---- barrier-free main loop: 128 MFMAs, operand-gated only ----
    #pragma unroll
    for (int itp = 0; itp < 4; ++itp) {
        LOADB(bB, 2 * itp + 1);
        MFMA_CHUNK(2 * itp, bA);
        if (itp < 3) LOADB(bA, 2 * itp + 2);
        MFMA_CHUNK(2 * itp + 1, bB);
    }

    // ---- epilogue: pair pp owned by waves (pp,c=0),(pp,c=1) ----
    float vmin = acc[0][0][0], vmax = vmin;
    #pragma unroll
    for (int ti = 0; ti < 4; ++ti)
        #pragma unroll
        for (int u = 0; u < 2; ++u)
            #pragma unroll
            for (int r = 0; r < 16; ++r) {
                vmin = fminf(vmin, acc[ti][u][r]);
                vmax = fmaxf(vmax, acc[ti][u][r]);
            }
    #pragma unroll
    for (int off = 1; off < 64; off <<= 1) {
        vmin = fminf(vmin, __shfl_xor(vmin, off, 64));
        vmax = fmaxf(vmax, __shfl_xor(vmax, off, 64));
    }
    if (lane == 0) { smin[w] = vmin; smax[w] = vmax; }
    __syncthreads();
    const float pmn = fminf(smin[pp * 2], smin[pp * 2 + 1]);
    const float pmx = fmaxf(smax[pp * 2], smax[pp * 2 + 1]);
    const float denom = (pmx > pmn) ? (pmx - pmn) : 1.0f;
    const float scale = 8.0f / denom;
    const float bias  = -pmn * scale;

    // per-thread packed histogram: 128 values -> 8-bit fields (<=128/bin)
    unsigned w0 = 0, w1 = 0;
    #pragma unroll
    for (int ti = 0; ti < 4; ++ti)
        #pragma unroll
        for (int u = 0; u < 2; ++u)
            #pragma unroll
            for (int r = 0; r < 16; ++r) {
                const float t = fmaf(acc[ti][u][r], scale, bias);
                int k = (int)t;          // t >= -eps; trunc == floor
                k = k > 7 ? 7 : k;
                const unsigned inc = 1u << ((k & 3) * 8);
                if (k < 4) w0 += inc; else w1 += inc;
            }
    unsigned e0 = (w0 & 0xFFu)         | (((w0 >> 8)  & 0xFFu) << 16);
    unsigned e1 = ((w0 >> 16) & 0xFFu) | (((w0 >> 24) & 0xFFu) << 16);
    unsigned e2 = (w1 & 0xFFu)         | (((w1 >> 8)  & 0xFFu) << 16);
    unsigned e3 = ((w1 >> 16) & 0xFFu) | (((w1 >> 24) & 0xFFu) << 16);
    #pragma unroll
    for (int off = 32; off > 0; off >>= 1) {
        e0 += __shfl_down(e0, off, 64);
        e1 += __shfl_down(e1, off, 64);
        e2 += __shfl_down(e2, off, 64);
        e3 += __shfl_down(e3, off, 64);
    }
    if (lane == 0) {
        atomicAdd(&hist[pp][0], (int)(e0 & 0xFFFFu)); atomicAdd(&hist[pp][1], (int)(e0 >> 16));
        atomicAdd(&hist[pp][2], (int)(e1 & 0xFFFFu)); atomicAdd(&hist[pp][3], (int)(e1 >> 16));
        atomicAdd(&hist[pp][4], (int)(e2 & 0xFFFFu)); atomicAdd(&hist[pp][5], (int)(e2 >> 16));
        atomicAdd(&hist[pp][6], (int)(e3 & 0xFFFFu)); atomicAdd(&hist[pp][7], (int)(e3 >> 16));
    }
    __syncthreads();

    // one wave per pair normalizes and writes both symmetric rows
    const int B = (pp == 0) ? b1 : b2;
    const bool valid = (pp == 0) || b2valid;
    if (valid && c == 0 && lane < 8) {
        float ss = 0.0f;
        #pragma unroll
        for (int k = 0; k < 8; ++k) {
            const float cc = (float)hist[pp][k];
            ss += cc * cc;
        }
        const float nrm = fmaxf(sqrtf(ss), 1e-12f);
        const float v = (float)hist[pp][lane] / nrm;
        out[((size_t)a * BS + B) * 16 + mat * 8 + lane] = v;
        if (a != B)
            out[((size_t)B * BS + a) * 16 + mat * 8 + lane] = v;
    }
}

extern "C" void kernel_launch(void* const* d_in, const int* in_sizes, int n_in,
                              void* d_out, int out_size, void* d_ws, size_t ws_size,
                              hipStream_t stream) {
    const float* m1 = (const float*)d_in[0];
    const float* m2 = (const float*)d_in[1];
    float* out = (float*)d_out;

    // Workspace: granule-major fp16 array, 2*64*128*256 u16 = 8.39 MB.
    u16* hT = (u16*)d_ws;

    convert_f16_kernel<<<dim3(128, 4), 256, 0, stream>>>(m1, m2, hT);
    gram_hist_mfma<<<dim3(NBP, 2), 256, 0, stream>>>(hT, out);
}

// Round 4
// 113.182 us; speedup vs baseline: 1.0398x; 1.0255x over previous
//
#include <hip/hip_runtime.h>
#include <math.h>

// Problem constants (from reference setup_inputs)
#define BS 64      // batch
#define F  256     // features (K of the Gram matmul)
#define M  128     // columns  (M=N of the Gram matmul)
#define MF (M * F) // u16 elements per matrix in hT
#define NBP 1056   // blocks per mat: sum_a ceil((64-a)/2)

typedef unsigned short u16;
typedef _Float16 f16x8 __attribute__((ext_vector_type(8)));
typedef float    f32x16 __attribute__((ext_vector_type(16)));

// ---------------------------------------------------------------------------
// Pre-pass: fp32 [f][m] -> fp16 GRANULE-MAJOR hT[b][f8][m][8]. (round 6:
// coalesced staging worth 107->58 us; layout verified.)
// ---------------------------------------------------------------------------
__global__ __launch_bounds__(256) void convert_f16_kernel(
    const float* __restrict__ m1, const float* __restrict__ m2,
    u16* __restrict__ hT)
{
    __shared__ float tile[64 * M];   // 32 KB
    const int mat = blockIdx.x >> 6;
    const int b   = blockIdx.x & 63;
    const int f0  = blockIdx.y * 64;
    const float* src = (mat == 0 ? m1 : m2) + (size_t)b * MF + (size_t)f0 * M;
    const int tid = threadIdx.x;

    const float4* g = (const float4*)src;
    float4* s = (float4*)tile;
    #pragma unroll
    for (int i = 0; i < 8; ++i)
        s[tid + i * 256] = g[tid + i * 256];
    __syncthreads();

    const size_t obase = ((size_t)(mat * BS + b) * 32 + (f0 >> 3)) * 1024;
    #pragma unroll
    for (int it = 0; it < 4; ++it) {
        const int idx = it * 256 + tid;
        const int f8l = idx >> 7;
        const int m   = idx & 127;
        u16 hh[8] __attribute__((aligned(16)));
        #pragma unroll
        for (int j = 0; j < 8; ++j) {
            const float x = tile[(f8l * 8 + j) * M + m];  // 2 lanes/bank: free
            const _Float16 h = (_Float16)x;               // RNE
            hh[j] = __builtin_bit_cast(u16, h);
        }
        *(uint4*)&hT[obase + (size_t)idx * 8] = *(const uint4*)hh;
    }
}

// ---------------------------------------------------------------------------
// ROUND 12 (latency-cover theory). Facts so far: MfmaUtil*dur invariant
// (14.3 us matrix-pipe floor); barriers not the stall (r11: 0-barrier,
// same 24% MfmaUtil); occupancy not the lever (r10); bandwidth not the
// wall (r10 pushed 11 TB/s and regressed). Remaining suspect: global-load
// LATENCY under-covered -- all prior structures gave loads ~1 MFMA-phase
// (~1024 shared-pipe cyc) before a FIFO vmcnt consume; L3 latency under
// contention ~1-2k cyc -> every wave in the block stalls together each
// period, which extra waves can't hide (they stall on the same loads).
// FIX: K-period = 64 (32 MFMAs per phase, ~2048 cyc cover), loads for
// period P+1 issued at TOP of period P's compute; A ds_write at END of
// period P (sched_barrier(0) pins it after the MFMA cluster so the
// compiler can't hoist the vmcnt wait into the cover window); barrier;
// period P+1 consumes. 4 barriers total, incremental A-staging (no r11
// up-front 64KB serial stage). s_setprio(1) around MFMA cluster (two
// independent barrier groups per CU -> phase-split regime where T5 pays).
// Regs: 128 AGPR acc + 64 B-frag + 16 A-stage + ~45 misc ~= 251 <= 256
// -> 2 waves/SIMD. LDS = 2 x 16 KB A double-buffer.
// ---------------------------------------------------------------------------

#define LOADB(DST, P) {                                               \
    const u16* pbk = pb + (P) * 8192;                                 \
    DST[0][0][0] = *(const f16x8*)(pbk);                              \
    DST[0][0][1] = *(const f16x8*)(pbk + 256);                        \
    DST[0][1][0] = *(const f16x8*)(pbk + 2048);                       \
    DST[0][1][1] = *(const f16x8*)(pbk + 2048 + 256);                 \
    DST[1][0][0] = *(const f16x8*)(pbk + 4096);                       \
    DST[1][0][1] = *(const f16x8*)(pbk + 4096 + 256);                 \
    DST[1][1][0] = *(const f16x8*)(pbk + 4096 + 2048);                \
    DST[1][1][1] = *(const f16x8*)(pbk + 4096 + 2048 + 256);          \
}

#define LOADA(P) {                                                    \
    const u16* pak = pa + (P) * 8192;                                 \
    rA0 = *(const uint4*)(pak);                                       \
    rA1 = *(const uint4*)(pak + 2048);                                \
    rA2 = *(const uint4*)(pak + 4096);                                \
    rA3 = *(const uint4*)(pak + 6144);                                \
}

#define WRITEA(BUF) {                                                 \
    *(uint4*)&lds[(BUF) + d0]        = rA0;                           \
    *(uint4*)&lds[(BUF) + 2048 + d0] = rA1;                           \
    *(uint4*)&lds[(BUF) + 4096 + d0] = rA2;                           \
    *(uint4*)&lds[(BUF) + 6144 + d0] = rA3;                           \
}

// One K=64 period: 2 sub-chunks (ITl) x [kk=0,1] x 4 ti x 2 u = 32 MFMAs.
#define MFMA_P(CUR, BF) {                                                                               \
    __builtin_amdgcn_s_setprio(1);                                                                      \
    _Pragma("unroll")                                                                                   \
    for (int ITl = 0; ITl < 2; ++ITl) {                                                                 \
        f16x8 af[4];                                                                                    \
        _Pragma("unroll")                                                                               \
        for (int t = 0; t < 4; ++t)                                                                     \
            af[t] = *(const f16x8*)&lds[(CUR) + ITl * 4096 + t * 256 + abase];                          \
        _Pragma("unroll")                                                                               \
        for (int ti = 0; ti < 4; ++ti) {                                                                \
            acc[ti][0] = __builtin_amdgcn_mfma_f32_32x32x16_f16(af[ti], BF[ITl][0][0], acc[ti][0], 0, 0, 0); \
            acc[ti][1] = __builtin_amdgcn_mfma_f32_32x32x16_f16(af[ti], BF[ITl][0][1], acc[ti][1], 0, 0, 0); \
        }                                                                                               \
        _Pragma("unroll")                                                                               \
        for (int t = 0; t < 4; ++t)                                                                     \
            af[t] = *(const f16x8*)&lds[(CUR) + ITl * 4096 + 2048 + t * 256 + abase];                   \
        _Pragma("unroll")                                                                               \
        for (int ti = 0; ti < 4; ++ti) {                                                                \
            acc[ti][0] = __builtin_amdgcn_mfma_f32_32x32x16_f16(af[ti], BF[ITl][1][0], acc[ti][0], 0, 0, 0); \
            acc[ti][1] = __builtin_amdgcn_mfma_f32_32x32x16_f16(af[ti], BF[ITl][1][1], acc[ti][1], 0, 0, 0); \
        }                                                                                               \
    }                                                                                                   \
    __builtin_amdgcn_s_setprio(0);                                                                      \
}

__global__ __launch_bounds__(256, 2) void gram_hist_mfma(
    const u16* __restrict__ hT, float* __restrict__ out)
{
    __shared__ u16 lds[2 * 8192];    // 32 KB: A K=64 periods, double-buffered
    __shared__ float smin[4], smax[4];
    __shared__ int hist[2][8];

    const int tid  = threadIdx.x;
    const int lane = tid & 63;
    const int w    = tid >> 6;

    if (tid < 16) hist[tid >> 3][tid & 7] = 0;

    // Decode blockIdx.x -> (a, p) with per-a count ceil((64-a)/2).
    int p = blockIdx.x, a = 0;
    { int cnt = 32; while (p >= cnt) { p -= cnt; ++a; cnt = (64 - a + 1) >> 1; } }
    const int b1 = a + 2 * p;
    int b2 = b1 + 1;
    const bool b2valid = (b2 <= 63);
    if (!b2valid) b2 = b1;          // duplicate work, writes suppressed
    const int mat = blockIdx.y;

    const int pp = w >> 1;     // which pair (0: b1, 1: b2)
    const int c  = w & 1;      // which 64-col half
    const int l31   = lane & 31;
    const int lhalf = lane >> 5;

    // A staging: thread copies 4 uint4 per period at u16 offs tid*8 + i*2048.
    const u16* pa = hT + (size_t)(mat * BS + a) * MF + tid * 8;
    const int d0 = tid * 8;

    // A fragment per-lane LDS base (u16 units).
    const int abase = lhalf * 1024 + l31 * 8;

    // B fragment per-lane global base (u16 units):
    //   frag(P,ITl,kk,u) = pb + P*8192 + ITl*4096 + kk*2048 + u*256
    const int bsel = pp ? b2 : b1;
    const u16* pb = hT + (size_t)(mat * BS + bsel) * MF
                  + (size_t)(lhalf * 1024 + c * 512 + l31 * 8);

    f32x16 acc[4][2];
    #pragma unroll
    for (int ti = 0; ti < 4; ++ti)
        #pragma unroll
        for (int u = 0; u < 2; ++u)
            #pragma unroll
            for (int r = 0; r < 16; ++r) acc[ti][u][r] = 0.0f;

    uint4 rA0, rA1, rA2, rA3;
    f16x8 bA[2][2][2], bB[2][2][2];   // double-buffered B fragment sets

    // ---- prologue: B0 + A0 (no cover -- paid once), write buf0 ----
    LOADB(bA, 0);
    LOADA(0);
    WRITEA(0);
    __syncthreads();

    // ---- 4 periods, unrolled by 2; loads for P+1 at TOP of period P ----
    // P0: compute buf0/bA, prefetch A1->buf1, B1->bB
    LOADA(1); LOADB(bB, 1);
    MFMA_P(0, bA);
    __builtin_amdgcn_sched_barrier(0);   // keep ds_write AFTER the cluster
    WRITEA(8192);
    __syncthreads();

    // P1: compute buf1/bB, prefetch A2->buf0, B2->bA
    LOADA(2); LOADB(bA, 2);
    MFMA_P(8192, bB);
    __builtin_amdgcn_sched_barrier(0);
    WRITEA(0);
    __syncthreads();

    // P2: compute buf0/bA, prefetch A3->buf1, B3->bB
    LOADA(3); LOADB(bB, 3);
    MFMA_P(0, bA);
    __builtin_amdgcn_sched_barrier(0);
    WRITEA(8192);
    __syncthreads();

    // P3: compute buf1/bB (no prefetch)
    MFMA_P(8192, bB);

    // ---- epilogue: pair pp owned by waves (pp,c=0),(pp,c=1) ----
    float vmin = acc[0][0][0], vmax = vmin;
    #pragma unroll
    for (int ti = 0; ti < 4; ++ti)
        #pragma unroll
        for (int u = 0; u < 2; ++u)
            #pragma unroll
            for (int r = 0; r < 16; ++r) {
                vmin = fminf(vmin, acc[ti][u][r]);
                vmax = fmaxf(vmax, acc[ti][u][r]);
            }
    #pragma unroll
    for (int off = 1; off < 64; off <<= 1) {
        vmin = fminf(vmin, __shfl_xor(vmin, off, 64));
        vmax = fmaxf(vmax, __shfl_xor(vmax, off, 64));
    }
    if (lane == 0) { smin[w] = vmin; smax[w] = vmax; }
    __syncthreads();
    const float pmn = fminf(smin[pp * 2], smin[pp * 2 + 1]);
    const float pmx = fmaxf(smax[pp * 2], smax[pp * 2 + 1]);
    const float denom = (pmx > pmn) ? (pmx - pmn) : 1.0f;
    const float scale = 8.0f / denom;
    const float bias  = -pmn * scale;

    // per-thread packed histogram: 128 values -> 8-bit fields (<=128/bin)
    unsigned w0 = 0, w1 = 0;
    #pragma unroll
    for (int ti = 0; ti < 4; ++ti)
        #pragma unroll
        for (int u = 0; u < 2; ++u)
            #pragma unroll
            for (int r = 0; r < 16; ++r) {
                const float t = fmaf(acc[ti][u][r], scale, bias);
                int k = (int)t;          // t >= -eps; trunc == floor
                k = k > 7 ? 7 : k;
                const unsigned inc = 1u << ((k & 3) * 8);
                if (k < 4) w0 += inc; else w1 += inc;
            }
    unsigned e0 = (w0 & 0xFFu)         | (((w0 >> 8)  & 0xFFu) << 16);
    unsigned e1 = ((w0 >> 16) & 0xFFu) | (((w0 >> 24) & 0xFFu) << 16);
    unsigned e2 = (w1 & 0xFFu)         | (((w1 >> 8)  & 0xFFu) << 16);
    unsigned e3 = ((w1 >> 16) & 0xFFu) | (((w1 >> 24) & 0xFFu) << 16);
    #pragma unroll
    for (int off = 32; off > 0; off >>= 1) {
        e0 += __shfl_down(e0, off, 64);
        e1 += __shfl_down(e1, off, 64);
        e2 += __shfl_down(e2, off, 64);
        e3 += __shfl_down(e3, off, 64);
    }
    if (lane == 0) {
        atomicAdd(&hist[pp][0], (int)(e0 & 0xFFFFu)); atomicAdd(&hist[pp][1], (int)(e0 >> 16));
        atomicAdd(&hist[pp][2], (int)(e1 & 0xFFFFu)); atomicAdd(&hist[pp][3], (int)(e1 >> 16));
        atomicAdd(&hist[pp][4], (int)(e2 & 0xFFFFu)); atomicAdd(&hist[pp][5], (int)(e2 >> 16));
        atomicAdd(&hist[pp][6], (int)(e3 & 0xFFFFu)); atomicAdd(&hist[pp][7], (int)(e3 >> 16));
    }
    __syncthreads();

    // one wave per pair normalizes and writes both symmetric rows
    const int B = (pp == 0) ? b1 : b2;
    const bool valid = (pp == 0) || b2valid;
    if (valid && c == 0 && lane < 8) {
        float ss = 0.0f;
        #pragma unroll
        for (int k = 0; k < 8; ++k) {
            const float cc = (float)hist[pp][k];
            ss += cc * cc;
        }
        const float nrm = fmaxf(sqrtf(ss), 1e-12f);
        const float v = (float)hist[pp][lane] / nrm;
        out[((size_t)a * BS + B) * 16 + mat * 8 + lane] = v;
        if (a != B)
            out[((size_t)B * BS + a) * 16 + mat * 8 + lane] = v;
    }
}

extern "C" void kernel_launch(void* const* d_in, const int* in_sizes, int n_in,
                              void* d_out, int out_size, void* d_ws, size_t ws_size,
                              hipStream_t stream) {
    const float* m1 = (const float*)d_in[0];
    const float* m2 = (const float*)d_in[1];
    float* out = (float*)d_out;

    // Workspace: granule-major fp16 array, 2*64*128*256 u16 = 8.39 MB.
    u16* hT = (u16*)d_ws;

    convert_f16_kernel<<<dim3(128, 4), 256, 0, stream>>>(m1, m2, hT);
    gram_hist_mfma<<<dim3(NBP, 2), 256, 0, stream>>>(hT, out);
}